// Round 1
// baseline (3586.420 us; speedup 1.0000x reference)
//
#include <hip/hip_runtime.h>
#include <math.h>

#define N_NODES 16384
#define DIM 32
#define SDIM 31
#define S_SEG 32
#define KSEG (N_NODES / S_SEG)   // 512
#define RPB 256                  // rows per block in spmm
#define KC 16                    // k-tile staged in LDS

// ---------------------------------------------------------------------------
// prep: build M_l = LW^T @ LWh  (32x32) for both layers.
// M[0][c]   = LWh[0][c]
// M[k][c]   = sum_{j>=1} W[j-1][k-1] * LWh[j][c]   (k >= 1)
// LWh[0][0]=ch, LWh[0][c]=sh*n[c-1], LWh[j][0]=sh*n[j-1],
// LWh[j][c]=(j==c) - (1-ch)*n[j-1]*n[c-1]
// ---------------------------------------------------------------------------
__global__ void prep_kernel(const float* __restrict__ Ws, const float* __restrict__ Hs,
                            float* __restrict__ Mout) {
    __shared__ float LWh[DIM][DIM];
    __shared__ float nsh[SDIM];
    __shared__ float sc[2];
    const int tid = threadIdx.x;
    for (int l = 0; l < 2; ++l) {
        const float* h = Hs + l * DIM;
        const float* W = Ws + l * SDIM * SDIM;
        if (tid == 0) {
            float s = 0.f;
            for (int i = 0; i < SDIM; ++i) { float v = h[1 + i]; s += v * v; }
            float rn = 1.0f / sqrtf(s + 1e-14f);
            for (int i = 0; i < SDIM; ++i) nsh[i] = h[1 + i] * rn;
            sc[0] = coshf(h[0]);
            sc[1] = sinhf(h[0]);
        }
        __syncthreads();
        const int j = tid >> 5, c = tid & 31;
        const float ch = sc[0], sh = sc[1];
        float val;
        if (j == 0)       val = (c == 0) ? ch : sh * nsh[c - 1];
        else if (c == 0)  val = sh * nsh[j - 1];
        else              val = ((j == c) ? 1.0f : 0.0f) - (1.0f - ch) * nsh[j - 1] * nsh[c - 1];
        LWh[j][c] = val;
        __syncthreads();
        const int k = j;
        float m;
        if (k == 0) {
            m = LWh[0][c];
        } else {
            m = 0.f;
            for (int jj = 1; jj < DIM; ++jj)
                m = fmaf(W[(jj - 1) * SDIM + (k - 1)], LWh[jj][c], m);
        }
        Mout[l * 1024 + k * DIM + c] = m;
        __syncthreads();
    }
}

// ---------------------------------------------------------------------------
// msg: msg = x @ M1   (16384x32 @ 32x32). Also zero the support accumulator.
// ---------------------------------------------------------------------------
__global__ __launch_bounds__(256) void msg_kernel(const float* __restrict__ x,
                                                  const float* __restrict__ M,
                                                  float* __restrict__ msg,
                                                  float* __restrict__ support_zero) {
    __shared__ float Ms[DIM][DIM];
    __shared__ float xs[8][DIM];
    const int tid = threadIdx.x;
    const int base = blockIdx.x * 8;
    reinterpret_cast<float4*>(&Ms[0][0])[tid] = reinterpret_cast<const float4*>(M)[tid];
    reinterpret_cast<float*>(xs)[tid] = x[(size_t)base * DIM + tid];
    support_zero[(size_t)blockIdx.x * 256 + tid] = 0.0f;
    __syncthreads();
    const int r = tid >> 5, c = tid & 31;
    float acc = 0.f;
#pragma unroll
    for (int k = 0; k < DIM; ++k) acc = fmaf(xs[r][k], Ms[k][c], acc);
    msg[(size_t)(base + r) * DIM + c] = acc;
}

// ---------------------------------------------------------------------------
// spmm: support += adj[rows, kseg] @ msg[kseg, :]   (split-K, atomic epilogue)
// Thread owns one row, 32 f32 accumulators. adj tile staged in LDS (pad +1:
// bank = (17*tid+kk)%32 -> 2-way on reads, free). msg row is wave-uniform ->
// s_load, FMA takes the SGPR operand slot.
// Occupancy is the lever this round: S_SEG=32 -> 2048 blocks = 8 blocks/CU;
// KC=16 -> tile = 17 KB so LDS allows 9 blocks/CU; __launch_bounds__(256,8)
// holds VGPR <= 64 so all 32 wave slots/CU fill (was 2 blocks/CU, 13% VALUBusy).
// ---------------------------------------------------------------------------
__global__ __launch_bounds__(256, 8) void spmm_kernel(const float* __restrict__ adj,
                                                      const float* __restrict__ msg,
                                                      float* __restrict__ support) {
    __shared__ float tile[RPB][KC + 1];
    const int tid = threadIdx.x;
    const int rowbase = blockIdx.y * RPB;
    const int k0 = blockIdx.x * KSEG;

    float acc[DIM];
#pragma unroll
    for (int c = 0; c < DIM; ++c) acc[c] = 0.f;

    for (int kt = 0; kt < KSEG; kt += KC) {
        __syncthreads();
        // stage 256 rows x 16 k: 1024 float4, 4 per thread, 64B/row segments
        // (other half of each 128B line is this block's next tile -> L2-hot)
#pragma unroll
        for (int it = 0; it < (RPB * KC / 4) / 256; ++it) {
            const int i = tid + it * 256;
            const int row = i >> 2;          // KC/4 = 4 float4 per row
            const int kq = (i & 3) << 2;
            const float4 v = *reinterpret_cast<const float4*>(
                adj + (size_t)(rowbase + row) * N_NODES + (k0 + kt + kq));
            tile[row][kq + 0] = v.x;
            tile[row][kq + 1] = v.y;
            tile[row][kq + 2] = v.z;
            tile[row][kq + 3] = v.w;
        }
        __syncthreads();
        const float* mrow = msg + (size_t)(k0 + kt) * DIM;
#pragma unroll 4
        for (int kk = 0; kk < KC; ++kk) {
            const float a = tile[tid][kk];
#pragma unroll
            for (int c = 0; c < DIM; ++c)
                acc[c] = fmaf(a, mrow[kk * DIM + c], acc[c]);
        }
    }

    float* srow = support + (size_t)(rowbase + tid) * DIM;
#pragma unroll
    for (int c = 0; c < DIM; ++c) unsafeAtomicAdd(srow + c, acc[c]);
}

// ---------------------------------------------------------------------------
// post: per-row minkowski normalize + selu + Poincare->hyperboloid projection.
// do_msg=1: also fuse next layer's msg = x_out @ M2 and re-zero support.
// ---------------------------------------------------------------------------
__global__ __launch_bounds__(256) void post_kernel(const float* __restrict__ support,
                                                   const float* __restrict__ M2,
                                                   float* __restrict__ outbuf,
                                                   float* __restrict__ support_zero,
                                                   const int do_msg) {
    __shared__ float Ms[DIM][DIM];
    __shared__ float xo[8][DIM];
    const int tid = threadIdx.x;
    const int base = blockIdx.x * 8;
    if (do_msg)
        reinterpret_cast<float4*>(&Ms[0][0])[tid] = reinterpret_cast<const float4*>(M2)[tid];
    const int r = tid >> 5, c = tid & 31;
    const size_t idx = (size_t)(base + r) * DIM + c;
    const float s = support[idx];

    float t = s * s;
    if (c == 0) t = -t;
    float mink = t;
#pragma unroll
    for (int m = 16; m >= 1; m >>= 1) mink += __shfl_xor(mink, m, 32);
    const float denom = sqrtf(fmaxf(fabsf(mink), 1e-8f));
    const float xx = s / denom;
    const float x0 = __shfl(xx, 0, 32);
    float p = 0.f;
    if (c != 0) {
        const float pp = xx / (x0 + 1.0f);
        const float scale = 1.0507009873554805f, alpha = 1.6732632423543772f;
        p = pp > 0.f ? scale * pp : scale * alpha * (expf(pp) - 1.0f);
    }
    float pn = p * p;
#pragma unroll
    for (int m = 16; m >= 1; m >>= 1) pn += __shfl_xor(pn, m, 32);
    const float inv = 1.0f / (1.0f - pn);
    const float o = (c == 0) ? (1.0f + pn) * inv : 2.0f * p * inv;

    if (do_msg) {
        xo[r][c] = o;
        support_zero[(size_t)blockIdx.x * 256 + tid] = 0.0f;
        __syncthreads();
        float acc = 0.f;
#pragma unroll
        for (int k = 0; k < DIM; ++k) acc = fmaf(xo[r][k], Ms[k][c], acc);
        outbuf[idx] = acc;
    } else {
        outbuf[idx] = o;
    }
}

// ---------------------------------------------------------------------------
extern "C" void kernel_launch(void* const* d_in, const int* in_sizes, int n_in,
                              void* d_out, int out_size, void* d_ws, size_t ws_size,
                              hipStream_t stream) {
    const float* node_repr = (const float*)d_in[0];
    const float* adj       = (const float*)d_in[1];
    const float* Ws        = (const float*)d_in[2];
    const float* Hs        = (const float*)d_in[3];
    float* out = (float*)d_out;
    float* ws  = (float*)d_ws;

    float* M1  = ws;                       // 1024 floats
    float* M2  = ws + 1024;                // 1024 floats
    float* msg = ws + 2048;                // 16384*32 floats (2 MB)
    float* sup = ws + 2048 + N_NODES * DIM; // 16384*32 floats (2 MB)

    prep_kernel<<<1, 1024, 0, stream>>>(Ws, Hs, M1);
    // layer 1
    msg_kernel<<<N_NODES / 8, 256, 0, stream>>>(node_repr, M1, msg, sup);
    spmm_kernel<<<dim3(S_SEG, N_NODES / RPB), 256, 0, stream>>>(adj, msg, sup);
    post_kernel<<<N_NODES / 8, 256, 0, stream>>>(sup, M2, msg, sup, 1); // writes msg2, zeroes sup
    // layer 2
    spmm_kernel<<<dim3(S_SEG, N_NODES / RPB), 256, 0, stream>>>(adj, msg, sup);
    post_kernel<<<N_NODES / 8, 256, 0, stream>>>(sup, M2, out, nullptr, 0);
}

// Round 2
// 2699.821 us; speedup vs baseline: 1.3284x; 1.3284x over previous
//
#include <hip/hip_runtime.h>
#include <math.h>

#define N_NODES 16384
#define DIM 32
#define SDIM 31
#define S_SEG 16
#define KSEG (N_NODES / S_SEG)   // 1024
#define RPB 256                  // rows per block in spmm
#define KC 32                    // k-tile staged in LDS

// ---------------------------------------------------------------------------
// prep: build M_l = LW^T @ LWh  (32x32) for both layers.
// M[0][c]   = LWh[0][c]
// M[k][c]   = sum_{j>=1} W[j-1][k-1] * LWh[j][c]   (k >= 1)
// LWh[0][0]=ch, LWh[0][c]=sh*n[c-1], LWh[j][0]=sh*n[j-1],
// LWh[j][c]=(j==c) - (1-ch)*n[j-1]*n[c-1]
// ---------------------------------------------------------------------------
__global__ void prep_kernel(const float* __restrict__ Ws, const float* __restrict__ Hs,
                            float* __restrict__ Mout) {
    __shared__ float LWh[DIM][DIM];
    __shared__ float nsh[SDIM];
    __shared__ float sc[2];
    const int tid = threadIdx.x;
    for (int l = 0; l < 2; ++l) {
        const float* h = Hs + l * DIM;
        const float* W = Ws + l * SDIM * SDIM;
        if (tid == 0) {
            float s = 0.f;
            for (int i = 0; i < SDIM; ++i) { float v = h[1 + i]; s += v * v; }
            float rn = 1.0f / sqrtf(s + 1e-14f);
            for (int i = 0; i < SDIM; ++i) nsh[i] = h[1 + i] * rn;
            sc[0] = coshf(h[0]);
            sc[1] = sinhf(h[0]);
        }
        __syncthreads();
        const int j = tid >> 5, c = tid & 31;
        const float ch = sc[0], sh = sc[1];
        float val;
        if (j == 0)       val = (c == 0) ? ch : sh * nsh[c - 1];
        else if (c == 0)  val = sh * nsh[j - 1];
        else              val = ((j == c) ? 1.0f : 0.0f) - (1.0f - ch) * nsh[j - 1] * nsh[c - 1];
        LWh[j][c] = val;
        __syncthreads();
        const int k = j;
        float m;
        if (k == 0) {
            m = LWh[0][c];
        } else {
            m = 0.f;
            for (int jj = 1; jj < DIM; ++jj)
                m = fmaf(W[(jj - 1) * SDIM + (k - 1)], LWh[jj][c], m);
        }
        Mout[l * 1024 + k * DIM + c] = m;
        __syncthreads();
    }
}

// ---------------------------------------------------------------------------
// msg: msg = x @ M1   (16384x32 @ 32x32). Also zero the support accumulator.
// ---------------------------------------------------------------------------
__global__ __launch_bounds__(256) void msg_kernel(const float* __restrict__ x,
                                                  const float* __restrict__ M,
                                                  float* __restrict__ msg,
                                                  float* __restrict__ support_zero) {
    __shared__ float Ms[DIM][DIM];
    __shared__ float xs[8][DIM];
    const int tid = threadIdx.x;
    const int base = blockIdx.x * 8;
    reinterpret_cast<float4*>(&Ms[0][0])[tid] = reinterpret_cast<const float4*>(M)[tid];
    reinterpret_cast<float*>(xs)[tid] = x[(size_t)base * DIM + tid];
    support_zero[(size_t)blockIdx.x * 256 + tid] = 0.0f;
    __syncthreads();
    const int r = tid >> 5, c = tid & 31;
    float acc = 0.f;
#pragma unroll
    for (int k = 0; k < DIM; ++k) acc = fmaf(xs[r][k], Ms[k][c], acc);
    msg[(size_t)(base + r) * DIM + c] = acc;
}

// ---------------------------------------------------------------------------
// spmm: support += adj[rows, kseg] @ msg[kseg, :]   (split-K, atomic epilogue)
// Thread owns one row, 32 f32 accumulators. adj tile staged in LDS (pad +1:
// bank = (33*tid+kk)%32 -> 2-way on wave64 reads, free). msg row is
// wave-uniform -> s_load, FMA takes the SGPR operand slot.
// Occupancy: S_SEG=16 -> 1024 blocks = 4 blocks/CU exactly; LDS 33792B x 4 =
// 132KB < 160KB; natural VGPR=52 <= 64 so no launch-bounds cap needed.
// (Round-1 lesson: forcing min-waves=8 capped VGPR<32 -> acc[32] spilled to
// scratch, FETCH doubled, VALUBusy fell to 9%. Never cap below acc size.)
// ---------------------------------------------------------------------------
__global__ __launch_bounds__(256) void spmm_kernel(const float* __restrict__ adj,
                                                   const float* __restrict__ msg,
                                                   float* __restrict__ support) {
    __shared__ float tile[RPB][KC + 1];
    const int tid = threadIdx.x;
    const int rowbase = blockIdx.y * RPB;
    const int k0 = blockIdx.x * KSEG;

    float acc[DIM];
#pragma unroll
    for (int c = 0; c < DIM; ++c) acc[c] = 0.f;

    for (int kt = 0; kt < KSEG; kt += KC) {
        __syncthreads();
        // stage 256 rows x 32 k: 2048 float4, 8 per thread, coalesced 128B/row
#pragma unroll
        for (int it = 0; it < (RPB * KC / 4) / 256; ++it) {
            const int i = tid + it * 256;
            const int row = i >> 3;          // KC/4 = 8 float4 per row
            const int kq = (i & 7) << 2;
            const float4 v = *reinterpret_cast<const float4*>(
                adj + (size_t)(rowbase + row) * N_NODES + (k0 + kt + kq));
            tile[row][kq + 0] = v.x;
            tile[row][kq + 1] = v.y;
            tile[row][kq + 2] = v.z;
            tile[row][kq + 3] = v.w;
        }
        __syncthreads();
        const float* mrow = msg + (size_t)(k0 + kt) * DIM;
#pragma unroll 4
        for (int kk = 0; kk < KC; ++kk) {
            const float a = tile[tid][kk];
#pragma unroll
            for (int c = 0; c < DIM; ++c)
                acc[c] = fmaf(a, mrow[kk * DIM + c], acc[c]);
        }
    }

    float* srow = support + (size_t)(rowbase + tid) * DIM;
#pragma unroll
    for (int c = 0; c < DIM; ++c) unsafeAtomicAdd(srow + c, acc[c]);
}

// ---------------------------------------------------------------------------
// post: per-row minkowski normalize + selu + Poincare->hyperboloid projection.
// do_msg=1: also fuse next layer's msg = x_out @ M2 and re-zero support.
// ---------------------------------------------------------------------------
__global__ __launch_bounds__(256) void post_kernel(const float* __restrict__ support,
                                                   const float* __restrict__ M2,
                                                   float* __restrict__ outbuf,
                                                   float* __restrict__ support_zero,
                                                   const int do_msg) {
    __shared__ float Ms[DIM][DIM];
    __shared__ float xo[8][DIM];
    const int tid = threadIdx.x;
    const int base = blockIdx.x * 8;
    if (do_msg)
        reinterpret_cast<float4*>(&Ms[0][0])[tid] = reinterpret_cast<const float4*>(M2)[tid];
    const int r = tid >> 5, c = tid & 31;
    const size_t idx = (size_t)(base + r) * DIM + c;
    const float s = support[idx];

    float t = s * s;
    if (c == 0) t = -t;
    float mink = t;
#pragma unroll
    for (int m = 16; m >= 1; m >>= 1) mink += __shfl_xor(mink, m, 32);
    const float denom = sqrtf(fmaxf(fabsf(mink), 1e-8f));
    const float xx = s / denom;
    const float x0 = __shfl(xx, 0, 32);
    float p = 0.f;
    if (c != 0) {
        const float pp = xx / (x0 + 1.0f);
        const float scale = 1.0507009873554805f, alpha = 1.6732632423543772f;
        p = pp > 0.f ? scale * pp : scale * alpha * (expf(pp) - 1.0f);
    }
    float pn = p * p;
#pragma unroll
    for (int m = 16; m >= 1; m >>= 1) pn += __shfl_xor(pn, m, 32);
    const float inv = 1.0f / (1.0f - pn);
    const float o = (c == 0) ? (1.0f + pn) * inv : 2.0f * p * inv;

    if (do_msg) {
        xo[r][c] = o;
        support_zero[(size_t)blockIdx.x * 256 + tid] = 0.0f;
        __syncthreads();
        float acc = 0.f;
#pragma unroll
        for (int k = 0; k < DIM; ++k) acc = fmaf(xo[r][k], Ms[k][c], acc);
        outbuf[idx] = acc;
    } else {
        outbuf[idx] = o;
    }
}

// ---------------------------------------------------------------------------
extern "C" void kernel_launch(void* const* d_in, const int* in_sizes, int n_in,
                              void* d_out, int out_size, void* d_ws, size_t ws_size,
                              hipStream_t stream) {
    const float* node_repr = (const float*)d_in[0];
    const float* adj       = (const float*)d_in[1];
    const float* Ws        = (const float*)d_in[2];
    const float* Hs        = (const float*)d_in[3];
    float* out = (float*)d_out;
    float* ws  = (float*)d_ws;

    float* M1  = ws;                       // 1024 floats
    float* M2  = ws + 1024;                // 1024 floats
    float* msg = ws + 2048;                // 16384*32 floats (2 MB)
    float* sup = ws + 2048 + N_NODES * DIM; // 16384*32 floats (2 MB)

    prep_kernel<<<1, 1024, 0, stream>>>(Ws, Hs, M1);
    // layer 1
    msg_kernel<<<N_NODES / 8, 256, 0, stream>>>(node_repr, M1, msg, sup);
    spmm_kernel<<<dim3(S_SEG, N_NODES / RPB), 256, 0, stream>>>(adj, msg, sup);
    post_kernel<<<N_NODES / 8, 256, 0, stream>>>(sup, M2, msg, sup, 1); // writes msg2, zeroes sup
    // layer 2
    spmm_kernel<<<dim3(S_SEG, N_NODES / RPB), 256, 0, stream>>>(adj, msg, sup);
    post_kernel<<<N_NODES / 8, 256, 0, stream>>>(sup, M2, out, nullptr, 0);
}